// Round 5
// baseline (153.900 us; speedup 1.0000x reference)
//
#include <hip/hip_runtime.h>
#include <hip/hip_bf16.h>

// Problem: V=50000, D=300, B=8, Q=128, W=16, L=8192
//   q_e[bq]   = sum_w emb[queries[bq,w]] / count(queries[bq,w]!=0)
//   sim[bq,l] = dot(q_e[bq], emb[labels[l]]) / max(|q_e[bq]|*|emb[labels[l]]|, 1e-8)
//   mask[bq,l]= (count!=0) && (labels[l]!=0)
// dtypes: emb float32, indices int32 (harness-converted), out float32.
// Output: sim (8,128,1,8192) then mask (8,128,1,8192) = 16,777,216 floats.

#define DD   300
#define DP   320          // K padded to multiple of 32 for MFMA
#define WQ   16
#define NQ   1024         // B*Q
#define NL   8192
#define EPSV 1e-8f

typedef __bf16 bf16_t;
typedef __attribute__((ext_vector_type(8))) __bf16 bf16x8;
typedef __attribute__((ext_vector_type(4))) float f32x4;
typedef __attribute__((ext_vector_type(4))) int i32x4;

// ---------- P: fused q_e + l_e build (bf16 padded rows, fp32 norms, flags) ----------
// blocks [0, NQ)     -> q path (gather 16 rows, avg, norm)
// blocks [NQ, NQ+NL) -> l path (gather 1 row, norm)
__global__ __launch_bounds__(320) void build_ql(const float* __restrict__ emb,
                                                const int* __restrict__ queries,
                                                const int* __restrict__ labels,
                                                bf16_t* __restrict__ qe,
                                                bf16_t* __restrict__ le,
                                                float* __restrict__ qn,
                                                float* __restrict__ lnrm,
                                                int* __restrict__ hasq,
                                                int* __restrict__ hasl) {
  const int blk = blockIdx.x;
  const int d = threadIdx.x;       // 0..319
  __shared__ float red[5];
  float v;                          // value whose square gets reduced

  if (blk < NQ) {
    // ----- query path -----
    int n = 0;
    int idx[WQ];
#pragma unroll
    for (int w = 0; w < WQ; ++w) {
      idx[w] = queries[blk * WQ + w];
      n += (idx[w] != 0) ? 1 : 0;
    }
    float s = 0.f;
    if (d < DD) {
#pragma unroll
      for (int w = 0; w < WQ; ++w)
        s += emb[(size_t)idx[w] * DD + d];
    }
    const float qv = (d < DD) ? (s / (float)n) : 0.f;
    qe[(size_t)blk * DP + d] = (bf16_t)qv;
    v = qv;
    if (d == 0) hasq[blk] = (n != 0) ? 1 : 0;
  } else {
    // ----- label path -----
    const int l = blk - NQ;
    const int r = labels[l];
    float lv = 0.f;
    if (d < DD) lv = emb[(size_t)r * DD + d];
    le[(size_t)l * DP + d] = (bf16_t)lv;
    v = lv;
    if (d == 0) hasl[l] = (r != 0) ? 1 : 0;
  }

  // block reduction of v^2 over 5 waves
  v = v * v;
#pragma unroll
  for (int off = 32; off > 0; off >>= 1) v += __shfl_down(v, off);
  if ((threadIdx.x & 63) == 0) red[threadIdx.x >> 6] = v;
  __syncthreads();
  if (threadIdx.x == 0) {
    const float nrm = sqrtf(red[0] + red[1] + red[2] + red[3] + red[4]);
    if (blk < NQ) qn[blk] = nrm; else lnrm[blk - NQ] = nrm;
  }
}

// ---------- G: TRANSPOSED-product MFMA GEMM, float4 coalesced epilogue ----------
// Computes D[l][q] = le . qe^T but stores to out[q][l].
// MFMA C layout: row m = quad*4+reg, col n = lane&15  (guide m89/m91, validated R2-R4).
// With A=le, B=qe: lane (quad,l16) holds l = ltile + quad*4 + {0..3} (CONSECUTIVE)
// and q = qtile + l16  ->  one float4 store per fragment at out[q*NL + l]. Fully
// coalesced 64B row-chunks per instruction, cached (L2 merges to full lines).
// Block: 64 l x 64 q, 4 waves each 32x32 (2x2 frags). 2048 blocks = 8/CU.
__global__ __launch_bounds__(256) void gemm_cos(const bf16_t* __restrict__ qe,
                                                const bf16_t* __restrict__ le,
                                                const float* __restrict__ qn,
                                                const float* __restrict__ lnrm,
                                                const int* __restrict__ hasq,
                                                const int* __restrict__ hasl,
                                                float* __restrict__ out) {
  const int l0 = blockIdx.x * 64;   // label-dim tile (MFMA m-dim)
  const int q0 = blockIdx.y * 64;   // query-dim tile (MFMA n-dim)
  const int wave = threadIdx.x >> 6;
  const int lane = threadIdx.x & 63;
  const int wl = (wave & 1) * 32;
  const int wq = (wave >> 1) * 32;
  const int l16 = lane & 15;
  const int quad = lane >> 4;

  f32x4 acc[2][2] = {};   // [i over l-tiles][j over q-tiles]

#pragma unroll 2
  for (int kb = 0; kb < 10; ++kb) {
    const int ko = kb * 32 + quad * 8;
    bf16x8 a[2], b[2];
#pragma unroll
    for (int i = 0; i < 2; ++i) {
      a[i] = *(const bf16x8*)(le + (size_t)(l0 + wl + i * 16 + l16) * DP + ko);
      b[i] = *(const bf16x8*)(qe + (size_t)(q0 + wq + i * 16 + l16) * DP + ko);
    }
#pragma unroll
    for (int i = 0; i < 2; ++i)
#pragma unroll
      for (int j = 0; j < 2; ++j)
        acc[i][j] = __builtin_amdgcn_mfma_f32_16x16x32_bf16(a[i], b[j], acc[i][j], 0, 0, 0);
  }

  // epilogue: per lane, l-base = l0+wl+i*16+quad*4 (4 consecutive l), q = q0+wq+j*16+l16
  float lv[2][4];
  int hl[2][4];
#pragma unroll
  for (int i = 0; i < 2; ++i) {
    const int lb = l0 + wl + i * 16 + quad * 4;
#pragma unroll
    for (int r = 0; r < 4; ++r) {
      lv[i][r] = lnrm[lb + r];
      hl[i][r] = hasl[lb + r];
    }
  }

  float* const outm = out + (size_t)NQ * NL;
#pragma unroll
  for (int j = 0; j < 2; ++j) {
    const int q = q0 + wq + j * 16 + l16;
    const float qv = qn[q];
    const int hq = hasq[q];
    const size_t rowb = (size_t)q * NL;
#pragma unroll
    for (int i = 0; i < 2; ++i) {
      const int lb = l0 + wl + i * 16 + quad * 4;
      f32x4 s, m;
#pragma unroll
      for (int r = 0; r < 4; ++r) {
        const float den = fmaxf(qv * lv[i][r], EPSV);
        s[r] = acc[i][j][r] * __builtin_amdgcn_rcpf(den);
        m[r] = (hq && hl[i][r]) ? 1.f : 0.f;
      }
      *(f32x4*)(out + rowb + lb) = s;
      *(f32x4*)(outm + rowb + lb) = m;
    }
  }
}

extern "C" void kernel_launch(void* const* d_in, const int* in_sizes, int n_in,
                              void* d_out, int out_size, void* d_ws, size_t ws_size,
                              hipStream_t stream) {
  const float* emb = (const float*)d_in[0];     // 50000 x 300 f32
  const int* queries = (const int*)d_in[1];     // 8*128*16 int32
  const int* labels = (const int*)d_in[2];      // 8192 int32

  char* ws = (char*)d_ws;
  bf16_t* qe   = (bf16_t*)(ws);                 // 1024*320*2  = 655360 B
  bf16_t* le   = (bf16_t*)(ws + 655360);        // 8192*320*2  = 5242880 B
  float*  qn   = (float*) (ws + 5898240);       // 1024*4
  float*  lnrm = (float*) (ws + 5902336);       // 8192*4
  int*    hasq = (int*)   (ws + 5935104);       // 1024*4
  int*    hasl = (int*)   (ws + 5939200);       // 8192*4  (end ~5.95 MB)

  float* out = (float*)d_out;

  build_ql<<<NQ + NL, 320, 0, stream>>>(emb, queries, labels, qe, le, qn, lnrm, hasq, hasl);
  gemm_cos<<<dim3(NL / 64, NQ / 64), 256, 0, stream>>>(qe, le, qn, lnrm, hasq, hasl, out);
}

// Round 6
// 129.723 us; speedup vs baseline: 1.1864x; 1.1864x over previous
//
#include <hip/hip_runtime.h>
#include <hip/hip_bf16.h>

// Problem: V=50000, D=300, B=8, Q=128, W=16, L=8192
//   q_e[bq]   = sum_w emb[queries[bq,w]] / count(queries[bq,w]!=0)
//   sim[bq,l] = dot(q_e[bq], emb[labels[l]]) / max(|q_e[bq]|*|emb[labels[l]]|, 1e-8)
//   mask[bq,l]= (count!=0) && (labels[l]!=0)
// dtypes: emb float32, indices int32 (harness-converted), out float32.
// Output: sim (8,128,1,8192) then mask (8,128,1,8192) = 16,777,216 floats.
//
// R6 design: qe/le stored in MFMA-FRAGMENT-MAJOR packed layout so every
// fragment load in the gemm is one contiguous 1KB per wave (no 64B-half-line
// scatter, which R4/R5 counters showed to be the latency/traffic bottleneck).
// Packed offset for (row r, dim d): g=r>>4, rr=r&15, kb=d>>5, quad=(d>>3)&3,
// e=d&7 ->  g*5120 + kb*512 + quad*128 + rr*8 + e.

#define DD   300
#define WQ   16
#define NQ   1024         // B*Q
#define NL   8192
#define EPSV 1e-8f
#define GSTRIDE 5120      // elems per 16-row packed group (16*320)

typedef __bf16 bf16_t;
typedef __attribute__((ext_vector_type(8))) __bf16 bf16x8;
typedef __attribute__((ext_vector_type(4))) float f32x4;

// ---------- P: fused q_e + l_e build -> packed layout + fp32 norms + flags ----------
// blocks [0, NQ)     -> q path (gather 16 rows, avg, norm)
// blocks [NQ, NQ+NL) -> l path (gather 1 row, norm)
__global__ __launch_bounds__(320) void build_ql(const float* __restrict__ emb,
                                                const int* __restrict__ queries,
                                                const int* __restrict__ labels,
                                                bf16_t* __restrict__ qep,
                                                bf16_t* __restrict__ lep,
                                                float* __restrict__ qn,
                                                float* __restrict__ lnrm,
                                                int* __restrict__ hasq,
                                                int* __restrict__ hasl) {
  const int blk = blockIdx.x;
  const int d = threadIdx.x;       // 0..319
  __shared__ float red[5];
  float v;                          // value whose square gets reduced

  // packed offset pieces for this (row, d)
  const int kb = d >> 5, quad = (d >> 3) & 3, e = d & 7;
  const size_t poff = (size_t)kb * 512 + quad * 128 + e;   // + g*GSTRIDE + rr*8

  if (blk < NQ) {
    // ----- query path -----
    int n = 0;
    int idx[WQ];
#pragma unroll
    for (int w = 0; w < WQ; ++w) {
      idx[w] = queries[blk * WQ + w];
      n += (idx[w] != 0) ? 1 : 0;
    }
    float s = 0.f;
    if (d < DD) {
#pragma unroll
      for (int w = 0; w < WQ; ++w)
        s += emb[(size_t)idx[w] * DD + d];
    }
    const float qv = (d < DD) ? (s / (float)n) : 0.f;
    qep[(size_t)(blk >> 4) * GSTRIDE + (blk & 15) * 8 + poff] = (bf16_t)qv;
    v = qv;
    if (d == 0) hasq[blk] = (n != 0) ? 1 : 0;
  } else {
    // ----- label path -----
    const int l = blk - NQ;
    const int r = labels[l];
    float lv = 0.f;
    if (d < DD) lv = emb[(size_t)r * DD + d];
    lep[(size_t)(l >> 4) * GSTRIDE + (l & 15) * 8 + poff] = (bf16_t)lv;
    v = lv;
    if (d == 0) hasl[l] = (r != 0) ? 1 : 0;
  }

  // block reduction of v^2 over 5 waves
  v = v * v;
#pragma unroll
  for (int off = 32; off > 0; off >>= 1) v += __shfl_down(v, off);
  if ((threadIdx.x & 63) == 0) red[threadIdx.x >> 6] = v;
  __syncthreads();
  if (threadIdx.x == 0) {
    const float nrm = sqrtf(red[0] + red[1] + red[2] + red[3] + red[4]);
    if (blk < NQ) qn[blk] = nrm; else lnrm[blk - NQ] = nrm;
  }
}

// ---------- G: 128l x 64q block, 4 waves each 32l x 64q; packed frag loads ----------
// Transposed product: A=le (m=l), B=qe (n=q). C layout: m = quad*4+reg, n = lane&15
// -> lane holds 4 CONSECUTIVE l for fixed q -> float4 stores to out[q][l].
// Every frag load: base + lane*16B = contiguous 1KB/wave from the packed arrays.
// 1024 blocks = 4/CU = 16 waves/CU; double-buffered register prefetch over kb.
__global__ __launch_bounds__(256) void gemm_cos(const bf16_t* __restrict__ qep,
                                                const bf16_t* __restrict__ lep,
                                                const float* __restrict__ qn,
                                                const float* __restrict__ lnrm,
                                                const int* __restrict__ hasq,
                                                const int* __restrict__ hasl,
                                                float* __restrict__ out) {
  const int l0 = blockIdx.x * 128;  // label tile (MFMA m)
  const int q0 = blockIdx.y * 64;   // query tile (MFMA n)
  const int wave = threadIdx.x >> 6;
  const int lane = threadIdx.x & 63;
  const int l16 = lane & 15;
  const int quad = lane >> 4;
  const int wl = wave * 32;         // this wave's l-offset within the block

  // packed bases: lane*8 elems = lane*16B within each (group,kb) 1KB blk
  const bf16_t* ap = lep + (size_t)((l0 >> 4) + wave * 2) * GSTRIDE + lane * 8;
  const bf16_t* bp = qep + (size_t)(q0 >> 4) * GSTRIDE + lane * 8;

  f32x4 acc[2][4] = {};   // [i over l-frags][j over q-frags]
  bf16x8 a[2][2], b[2][4];

#pragma unroll
  for (int i = 0; i < 2; ++i) a[0][i] = *(const bf16x8*)(ap + i * GSTRIDE);
#pragma unroll
  for (int j = 0; j < 4; ++j) b[0][j] = *(const bf16x8*)(bp + j * GSTRIDE);

#pragma unroll
  for (int kb = 0; kb < 10; ++kb) {
    const int cur = kb & 1, nxt = cur ^ 1;
    if (kb < 9) {
#pragma unroll
      for (int i = 0; i < 2; ++i)
        a[nxt][i] = *(const bf16x8*)(ap + i * GSTRIDE + (kb + 1) * 512);
#pragma unroll
      for (int j = 0; j < 4; ++j)
        b[nxt][j] = *(const bf16x8*)(bp + j * GSTRIDE + (kb + 1) * 512);
    }
#pragma unroll
    for (int i = 0; i < 2; ++i)
#pragma unroll
      for (int j = 0; j < 4; ++j)
        acc[i][j] = __builtin_amdgcn_mfma_f32_16x16x32_bf16(a[cur][i], b[cur][j],
                                                            acc[i][j], 0, 0, 0);
  }

  // epilogue: lane covers l = lb..lb+3 (consecutive), q = q0 + j*16 + l16
  float lv[2][4];
  int hl[2][4];
#pragma unroll
  for (int i = 0; i < 2; ++i) {
    const int lb = l0 + wl + i * 16 + quad * 4;
#pragma unroll
    for (int r = 0; r < 4; ++r) {
      lv[i][r] = lnrm[lb + r];
      hl[i][r] = hasl[lb + r];
    }
  }

  float* const outm = out + (size_t)NQ * NL;
#pragma unroll
  for (int j = 0; j < 4; ++j) {
    const int q = q0 + j * 16 + l16;
    const float qv = qn[q];
    const int hq = hasq[q];
    const size_t rowb = (size_t)q * NL;
#pragma unroll
    for (int i = 0; i < 2; ++i) {
      const int lb = l0 + wl + i * 16 + quad * 4;
      f32x4 s, m;
#pragma unroll
      for (int r = 0; r < 4; ++r) {
        const float den = fmaxf(qv * lv[i][r], EPSV);
        s[r] = acc[i][j][r] * __builtin_amdgcn_rcpf(den);
        m[r] = (hq && hl[i][r]) ? 1.f : 0.f;
      }
      *(f32x4*)(out + rowb + lb) = s;
      *(f32x4*)(outm + rowb + lb) = m;
    }
  }
}

extern "C" void kernel_launch(void* const* d_in, const int* in_sizes, int n_in,
                              void* d_out, int out_size, void* d_ws, size_t ws_size,
                              hipStream_t stream) {
  const float* emb = (const float*)d_in[0];     // 50000 x 300 f32
  const int* queries = (const int*)d_in[1];     // 8*128*16 int32
  const int* labels = (const int*)d_in[2];      // 8192 int32

  char* ws = (char*)d_ws;
  bf16_t* qep  = (bf16_t*)(ws);                 // 1024*320*2  = 655360 B (packed)
  bf16_t* lep  = (bf16_t*)(ws + 655360);        // 8192*320*2  = 5242880 B (packed)
  float*  qn   = (float*) (ws + 5898240);       // 1024*4
  float*  lnrm = (float*) (ws + 5902336);       // 8192*4
  int*    hasq = (int*)   (ws + 5935104);       // 1024*4
  int*    hasl = (int*)   (ws + 5939200);       // 8192*4  (end ~5.95 MB)

  float* out = (float*)d_out;

  build_ql<<<NQ + NL, 320, 0, stream>>>(emb, queries, labels, qep, lep, qn, lnrm, hasq, hasl);
  gemm_cos<<<dim3(NL / 128, NQ / 64), 256, 0, stream>>>(qep, lep, qn, lnrm, hasq, hasl, out);
}

// Round 7
// 125.840 us; speedup vs baseline: 1.2230x; 1.0309x over previous
//
#include <hip/hip_runtime.h>
#include <hip/hip_bf16.h>

// Problem: V=50000, D=300, B=8, Q=128, W=16, L=8192
//   q_e[bq]   = sum_w emb[queries[bq,w]] / count(queries[bq,w]!=0)
//   sim[bq,l] = dot(q_e[bq], emb[labels[l]]) / max(|q_e[bq]|*|emb[labels[l]]|, 1e-8)
//   mask[bq,l]= (count!=0) && (labels[l]!=0)
// dtypes: emb float32, indices int32 (harness-converted), out float32.
// Output: sim (8,128,1,8192) then mask (8,128,1,8192) = 16,777,216 floats.
//
// R6 proved fragment reads were the bottleneck (packed layout: 153.9->129.7us).
// R7: stage the packed 64q tile in LDS once per block (global_load_lds w=16,
// one barrier), b-frags via conflict-free ds_read_b128; only 2 dbl-buffered
// global a-frag loads per kb. Kills the 4x intra-block qe redundancy (248->125MB).
// Packed offset for (row r, dim d): g=r>>4, rr=r&15, kb=d>>5, quad=(d>>3)&3,
// e=d&7 ->  g*5120 + kb*512 + quad*128 + rr*8 + e.

#define DD   300
#define WQ   16
#define NQ   1024         // B*Q
#define NL   8192
#define EPSV 1e-8f
#define GSTRIDE 5120      // elems per 16-row packed group (16*320)

typedef __bf16 bf16_t;
typedef __attribute__((ext_vector_type(8))) __bf16 bf16x8;
typedef __attribute__((ext_vector_type(4))) float f32x4;

// ---------- P: fused q_e + l_e build -> packed layout + fp32 norms + flags ----------
__global__ __launch_bounds__(320) void build_ql(const float* __restrict__ emb,
                                                const int* __restrict__ queries,
                                                const int* __restrict__ labels,
                                                bf16_t* __restrict__ qep,
                                                bf16_t* __restrict__ lep,
                                                float* __restrict__ qn,
                                                float* __restrict__ lnrm,
                                                int* __restrict__ hasq,
                                                int* __restrict__ hasl) {
  const int blk = blockIdx.x;
  const int d = threadIdx.x;       // 0..319
  __shared__ float red[5];
  float v;

  const int kb = d >> 5, quad = (d >> 3) & 3, e = d & 7;
  const size_t poff = (size_t)kb * 512 + quad * 128 + e;   // + g*GSTRIDE + rr*8

  if (blk < NQ) {
    int n = 0;
    int idx[WQ];
#pragma unroll
    for (int w = 0; w < WQ; ++w) {
      idx[w] = queries[blk * WQ + w];
      n += (idx[w] != 0) ? 1 : 0;
    }
    float s = 0.f;
    if (d < DD) {
#pragma unroll
      for (int w = 0; w < WQ; ++w)
        s += emb[(size_t)idx[w] * DD + d];
    }
    const float qv = (d < DD) ? (s / (float)n) : 0.f;
    qep[(size_t)(blk >> 4) * GSTRIDE + (blk & 15) * 8 + poff] = (bf16_t)qv;
    v = qv;
    if (d == 0) hasq[blk] = (n != 0) ? 1 : 0;
  } else {
    const int l = blk - NQ;
    const int r = labels[l];
    float lv = 0.f;
    if (d < DD) lv = emb[(size_t)r * DD + d];
    lep[(size_t)(l >> 4) * GSTRIDE + (l & 15) * 8 + poff] = (bf16_t)lv;
    v = lv;
    if (d == 0) hasl[l] = (r != 0) ? 1 : 0;
  }

  v = v * v;
#pragma unroll
  for (int off = 32; off > 0; off >>= 1) v += __shfl_down(v, off);
  if ((threadIdx.x & 63) == 0) red[threadIdx.x >> 6] = v;
  __syncthreads();
  if (threadIdx.x == 0) {
    const float nrm = sqrtf(red[0] + red[1] + red[2] + red[3] + red[4]);
    if (blk < NQ) qn[blk] = nrm; else lnrm[blk - NQ] = nrm;
  }
}

// ---------- G: 128l x 64q block, 4 waves each 32l x 64q ----------
// qe tile (64q x 320 packed = 40KB) staged to LDS once (global_load_lds w=16),
// b-frags via ds_read_b128; a-frags direct packed global, double-buffered.
// Transposed product: A=le (m=l), B=qe (n=q); C: m=quad*4+reg (4 consecutive l),
// n=lane&15 (q) -> float4 stores to out[q][l]. 1024 blocks = 4/CU (LDS-capped).
__global__ __launch_bounds__(256) void gemm_cos(const bf16_t* __restrict__ qep,
                                                const bf16_t* __restrict__ lep,
                                                const float* __restrict__ qn,
                                                const float* __restrict__ lnrm,
                                                const int* __restrict__ hasq,
                                                const int* __restrict__ hasl,
                                                float* __restrict__ out) {
  const int l0 = blockIdx.x * 128;  // label tile (MFMA m)
  const int q0 = blockIdx.y * 64;   // query tile (MFMA n)
  const int wave = threadIdx.x >> 6;
  const int lane = threadIdx.x & 63;
  const int l16 = lane & 15;
  const int quad = lane >> 4;
  const int wl = wave * 32;         // this wave's l-offset within the block

  __shared__ __align__(16) bf16_t qls[4 * GSTRIDE];   // 20480 elems = 40 KB

  // ---- stage packed qe tile (4 consecutive groups, fully contiguous) ----
  {
    const char* gsrc = (const char*)(qep + (size_t)(q0 >> 4) * GSTRIDE);
    char* lbase = (char*)qls;
#pragma unroll
    for (int t = 0; t < 10; ++t) {
      const int boff = (t * 256 + threadIdx.x) * 16;
      __builtin_amdgcn_global_load_lds(
          (const __attribute__((address_space(1))) void*)(gsrc + boff),
          (__attribute__((address_space(3))) void*)(lbase + boff),
          16, 0, 0);
    }
  }

  // a-frag base (this wave's two 16-row l-groups)
  const bf16_t* ap = lep + (size_t)((l0 >> 4) + wave * 2) * GSTRIDE + lane * 8;

  f32x4 acc[2][4] = {};   // [i over l-frags][j over q-frags]
  bf16x8 a[2][2];

  __syncthreads();        // LDS tile ready (also drains global_load_lds via barrier wait)

#pragma unroll
  for (int i = 0; i < 2; ++i) a[0][i] = *(const bf16x8*)(ap + i * GSTRIDE);

#pragma unroll
  for (int kb = 0; kb < 10; ++kb) {
    const int cur = kb & 1, nxt = cur ^ 1;
    if (kb < 9) {
#pragma unroll
      for (int i = 0; i < 2; ++i)
        a[nxt][i] = *(const bf16x8*)(ap + i * GSTRIDE + (kb + 1) * 512);
    }
    bf16x8 b[4];
#pragma unroll
    for (int j = 0; j < 4; ++j)
      b[j] = *(const bf16x8*)(qls + (size_t)j * GSTRIDE + kb * 512 + lane * 8);
#pragma unroll
    for (int i = 0; i < 2; ++i)
#pragma unroll
      for (int j = 0; j < 4; ++j)
        acc[i][j] = __builtin_amdgcn_mfma_f32_16x16x32_bf16(a[cur][i], b[j],
                                                            acc[i][j], 0, 0, 0);
  }

  // ---- epilogue: lane covers l = lb..lb+3 (consecutive), q = q0 + j*16 + l16 ----
  float lv[2][4];
  int hl[2][4];
#pragma unroll
  for (int i = 0; i < 2; ++i) {
    const int lb = l0 + wl + i * 16 + quad * 4;
#pragma unroll
    for (int r = 0; r < 4; ++r) {
      lv[i][r] = lnrm[lb + r];
      hl[i][r] = hasl[lb + r];
    }
  }

  float* const outm = out + (size_t)NQ * NL;
#pragma unroll
  for (int j = 0; j < 4; ++j) {
    const int q = q0 + j * 16 + l16;
    const float qv = qn[q];
    const int hq = hasq[q];
    const size_t rowb = (size_t)q * NL;
#pragma unroll
    for (int i = 0; i < 2; ++i) {
      const int lb = l0 + wl + i * 16 + quad * 4;
      f32x4 s, m;
#pragma unroll
      for (int r = 0; r < 4; ++r) {
        const float den = fmaxf(qv * lv[i][r], EPSV);
        s[r] = acc[i][j][r] * __builtin_amdgcn_rcpf(den);
        m[r] = (hq && hl[i][r]) ? 1.f : 0.f;
      }
      *(f32x4*)(out + rowb + lb) = s;
      *(f32x4*)(outm + rowb + lb) = m;
    }
  }
}

extern "C" void kernel_launch(void* const* d_in, const int* in_sizes, int n_in,
                              void* d_out, int out_size, void* d_ws, size_t ws_size,
                              hipStream_t stream) {
  const float* emb = (const float*)d_in[0];     // 50000 x 300 f32
  const int* queries = (const int*)d_in[1];     // 8*128*16 int32
  const int* labels = (const int*)d_in[2];      // 8192 int32

  char* ws = (char*)d_ws;
  bf16_t* qep  = (bf16_t*)(ws);                 // 1024*320*2  = 655360 B (packed)
  bf16_t* lep  = (bf16_t*)(ws + 655360);        // 8192*320*2  = 5242880 B (packed)
  float*  qn   = (float*) (ws + 5898240);       // 1024*4
  float*  lnrm = (float*) (ws + 5902336);       // 8192*4
  int*    hasq = (int*)   (ws + 5935104);       // 1024*4
  int*    hasl = (int*)   (ws + 5939200);       // 8192*4  (end ~5.95 MB)

  float* out = (float*)d_out;

  build_ql<<<NQ + NL, 320, 0, stream>>>(emb, queries, labels, qep, lep, qn, lnrm, hasq, hasl);
  gemm_cos<<<dim3(NL / 128, NQ / 64), 256, 0, stream>>>(qep, lep, qn, lnrm, hasq, hasl, out);
}